// Round 9
// baseline (204.254 us; speedup 1.0000x reference)
//
#include <hip/hip_runtime.h>
#include <hip/hip_fp16.h>
#include <math.h>

#define FLT_BIG 3.402823466e38f
typedef unsigned int uint;
typedef unsigned short ushort;
typedef __attribute__((ext_vector_type(8))) _Float16 half8;  // 8 fp16 (4 VGPRs)
typedef __attribute__((ext_vector_type(4))) float floatx4;   // MFMA C/D frag

__device__ inline ushort f2h(float f) {   // fp16 RNE, 1 instr (v_cvt_f16_f32)
    return __half_as_ushort(__float2half(f));
}
// packed 2xfp16 dot with f32 accumulate: d = a.h0*b.h0 + a.h1*b.h1 + c
__device__ inline float dot2(uint a, uint b, float c) {
    float d;
    asm("v_dot2_f32_f16 %0, %1, %2, %3" : "=v"(d) : "v"(a), "v"(b), "v"(c));
    return d;
}
// DPP cross-lane read (VALU pipe, not DS). CTRL: 0x120+N=row_ror:N,
// 0x140=row_mirror (xor15), 0x141=row_half_mirror (xor7 within 8),
// 0x4E=quad_perm[2,3,0,1] (xor2), 0xB1=quad_perm[1,0,3,2] (xor1).
template <int CTRL>
__device__ inline float dppf(float x) {
    return __int_as_float(__builtin_amdgcn_update_dpp(
        __float_as_int(x), __float_as_int(x), CTRL, 0xF, 0xF, true));
}

// ---------------------------------------------------------------- prep + min
// Table/W transposes (fp16) + grid-stride xyz-min with atomicMin.
// mn is pre-initialized to 0x7F7F7F7F (3.396e38) by hipMemsetAsync.
__global__ void prep_min_kernel(const float* __restrict__ W_qkv,
                                const float* __restrict__ W_proj,
                                const float* __restrict__ tq, const float* __restrict__ tk,
                                const float* __restrict__ tv,
                                const float* __restrict__ xyz,
                                ushort* __restrict__ wtqkv, ushort* __restrict__ wtproj,
                                ushort* __restrict__ rq, ushort* __restrict__ rk,
                                ushort* __restrict__ rv, float* mn, int n) {
    int tid = blockIdx.x * 256 + threadIdx.x;
    if (tid < 18432) {  // tables: 3*64*96 -> [c][idx][hd] fp16
        int c = tid / 6144, rem = tid - c * 6144;
        int idx = rem / 96, hd = rem - idx * 96;
        int src = (idx * 96 + hd) * 3 + c;
        rq[tid] = f2h(tq[src]);
        rk[tid] = f2h(tk[src]);
        rv[tid] = f2h(tv[src]);
    }
    if (tid < 27648) {  // WT_qkv[j][d] = W_qkv[d][j], j over 288
        int j = tid / 96, d = tid - j * 96;
        wtqkv[tid] = f2h(W_qkv[d * 288 + j]);
    }
    if (tid < 9216) {   // WT_proj[j][d] = W_proj[d][j]
        int j = tid / 96, d = tid - j * 96;
        wtproj[tid] = f2h(W_proj[d * 96 + j]);
    }
    // grid-stride min partials -> wave reduce -> atomicMin (mn preset big)
    float m0 = FLT_BIG, m1 = FLT_BIG, m2 = FLT_BIG;
    for (int i = tid; i < n; i += gridDim.x * 256) {
        m0 = fminf(m0, xyz[3 * i + 0]);
        m1 = fminf(m1, xyz[3 * i + 1]);
        m2 = fminf(m2, xyz[3 * i + 2]);
    }
#pragma unroll
    for (int off = 32; off > 0; off >>= 1) {
        m0 = fminf(m0, __shfl_down(m0, off));
        m1 = fminf(m1, __shfl_down(m1, off));
        m2 = fminf(m2, __shfl_down(m2, off));
    }
    if ((threadIdx.x & 63) == 0) {
        // xyz >= 0 so float bits are monotone under signed int compare
        atomicMin((int*)&mn[0], __float_as_int(m0));
        atomicMin((int*)&mn[1], __float_as_int(m1));
        atomicMin((int*)&mn[2], __float_as_int(m2));
    }
}

// ---------------------------------------------------------------- QKV MFMA GEMM
// ONE pass over A: 384-thread block covers 64 rows; A tile cvt'd fp32->fp16
// ONCE into LDS (pitch 104 ushorts), then 6 waves = 3 channels x 2 row-groups
// consume via ds_read_b128. 56KB LDS -> 2 blocks/CU. Threads 0..63 also
// compute packed quantized coords xq[p] (mn ready by stream order).
__global__ __launch_bounds__(384) void qkv_mfma_kernel(
    const float* __restrict__ A, const ushort* __restrict__ WT,
    const float* __restrict__ bias, uint4* __restrict__ qout4,
    uint4* __restrict__ kvout4, const float* __restrict__ xyz,
    const float* __restrict__ mn, const float* __restrict__ shiftp,
    uint* __restrict__ xq, int n) {
    __shared__ ushort Ash[64 * 104];     // 13312 B: A tile fp16, pitch 208B
    __shared__ ushort lds[6][32 * 112];  // 43008 B: per-wave epilogue repack
    const int t = threadIdx.x;
    const int row0 = blockIdx.x * 64;

    if (t < 64) {
        int rp = row0 + t;
        if (rp < n) {
            float shift = shiftp[0];
            float q0 = floorf(fmodf(xyz[3 * rp + 0] - mn[0] + shift, 4.0f) * 4.0f);
            float q1 = floorf(fmodf(xyz[3 * rp + 1] - mn[1] + shift, 4.0f) * 4.0f);
            float q2 = floorf(fmodf(xyz[3 * rp + 2] - mn[2] + shift, 4.0f) * 4.0f);
            xq[rp] = (uint)(int)q0 | ((uint)(int)q1 << 8) | ((uint)(int)q2 << 16);
        }
    }

    // ---- stage A tile: 64 rows x 24 float4 = 1536 chunks, 4 per thread
    const float4* A4 = (const float4*)A;
#pragma unroll
    for (int j = 0; j < 4; j++) {
        int idx = t + j * 384;
        int row = idx / 24, c4 = idx - row * 24;
        int gr = row0 + row; if (gr > n - 1) gr = n - 1;
        float4 v = A4[(size_t)gr * 24 + c4];
        uint2 pk;
        pk.x = (uint)f2h(v.x) | ((uint)f2h(v.y) << 16);
        pk.y = (uint)f2h(v.z) | ((uint)f2h(v.w) << 16);
        *(uint2*)&Ash[row * 104 + c4 * 4] = pk;
    }
    __syncthreads();

    const int wave = t >> 6, lane = t & 63;
    const int ch = wave >> 1, rg = wave & 1;  // 3 channels x 2 row-groups
    const int m = lane & 15, q = lane >> 4;
    const int wrow0 = row0 + rg * 32;

    const ushort* wbase = WT + ((size_t)ch * 96 + m) * 96 + q * 8;

    floatx4 acc[2][6];
#pragma unroll
    for (int g = 0; g < 2; g++)
#pragma unroll
        for (int ct = 0; ct < 6; ct++) acc[g][ct] = (floatx4){0.f, 0.f, 0.f, 0.f};

#pragma unroll
    for (int kk4 = 0; kk4 < 24; kk4 += 8) {  // k offset in float4 units
        half8 a0 = *(const half8*)&Ash[(rg * 32 + m) * 104 + (kk4 + q * 2) * 4];
        half8 a1 = *(const half8*)&Ash[(rg * 32 + 16 + m) * 104 + (kk4 + q * 2) * 4];
#pragma unroll
        for (int ct = 0; ct < 6; ct++) {
            half8 b = *(const half8*)(wbase + ct * 16 * 96 + kk4 * 4);
            acc[0][ct] = __builtin_amdgcn_mfma_f32_16x16x32_f16(a0, b, acc[0][ct], 0, 0, 0);
            acc[1][ct] = __builtin_amdgcn_mfma_f32_16x16x32_f16(a1, b, acc[1][ct], 0, 0, 0);
        }
    }

    ushort* L = lds[wave];
    const float sc = (ch == 0) ? 0.25f : 1.0f;
#pragma unroll
    for (int g = 0; g < 2; g++)
#pragma unroll
        for (int ct = 0; ct < 6; ct++) {
            float bv = bias[ch * 96 + ct * 16 + m];
#pragma unroll
            for (int r = 0; r < 4; r++) {
                int rowl = g * 16 + q * 4 + r;
                L[rowl * 112 + ct * 16 + m] = f2h((acc[g][ct][r] + bv) * sc);
            }
        }
    // wave-internal LDS RAW: compiler inserts lgkmcnt wait, no barrier needed
    const int strideU4 = (ch == 0) ? 12 : 24;
    const int offU4 = (ch == 2) ? 12 : 0;
    uint4* dst = (ch == 0) ? qout4 : kvout4;
#pragma unroll
    for (int i = 0; i < 6; i++) {
        int idx = i * 64 + lane;  // 0..383 over 32 rows x 12 uint4
        int rowl = idx / 12, u4 = idx - rowl * 12;
        int grow = wrow0 + rowl;
        if (grow < n) {
            uint4 val = *(const uint4*)(L + rowl * 112 + u4 * 8);
            dst[(size_t)grow * strideU4 + offU4 + u4] = val;
        }
    }
}

// ---------------------------------------------------------------- attn + proj
// One 768-thread block per CU (grid 256). LDS: rq/rk pitch 208, rv pitch 192
// (116736 B) + x-stash 208 rows x 208 B (43264 B) = 160000 B.
// TWO-STREAM INTERLEAVE (T15): each thread processes 2 points/iter (u=0,1;
// 16 points/block-iter, 13 iters). All phase loops are #pragma unroll over u
// with compile-time indices (no scratch). Two independent dependency chains
// let the serial DPP softmax / PV-butterfly of one stream hide under the
// dot2s of the other -> lifts both VALU and DS utilization from ~50%.
// table_v fold: pre-sum the 3 table rows with v_pk_add_f16 (err ~3e-5),
// v stays fp32. x rows land in LDS; proj runs per-block after one barrier.
#define ATTN_NB 256
#define PPB 16
#define QPITCH 208
#define VPITCH 192
#define KOFF 39936   // 192 rows x 208
#define VOFF 79872   // + 192 rows x 208
#define XOFF 116736  // + 192 rows x 192
#define XPITCH 104   // ushorts (208 B)
__global__ __launch_bounds__(768, 3) void attn_proj_kernel(
    const ushort* __restrict__ qh, const ushort* __restrict__ kv,
    const uint* __restrict__ xq, const int* __restrict__ index_1,
    const ushort* __restrict__ rq, const ushort* __restrict__ rk,
    const ushort* __restrict__ rv, const ushort* __restrict__ wtproj,
    const float* __restrict__ b_proj, float* __restrict__ out, int n) {
    __shared__ __align__(16) char Lb[160000];

    const int t = threadIdx.x, b = blockIdx.x;
    const int pt = t / 96, tp = t - pt * 96;
    const int h = tp >> 4, e = tp & 15;

    const int stride = ATTN_NB * PPB;                      // 4096
    const int iters = (n + stride - 1) / stride;           // 13

    // ---- 2-stage x 2-stream prefetch state
    int pA[2], jdA[2]; uint xqpA[2];                       // stage A: indices
    auto PREF_A = [&](int it, int u) {
        pA[u] = (it * ATTN_NB + b) * PPB + u * 8 + pt;
        int pc = pA[u] < n ? pA[u] : n - 1;
        jdA[u] = index_1[(size_t)pc * 16 + e];
        xqpA[u] = xq[pc];
    };
    int p[2], jd[2]; uint xqp[2], xqj[2];                  // stage B: rows
    uint4 ka[2], kb[2], va[2], vb[2], qa[2], qb[2];
    auto PREF_B = [&](int u) {
        p[u] = pA[u]; jd[u] = jdA[u]; xqp[u] = xqpA[u];
        int pc = p[u] < n ? p[u] : n - 1;
        const ushort* row = kv + (size_t)jd[u] * 192;
        ka[u] = *(const uint4*)(row + h * 16);
        kb[u] = *(const uint4*)(row + h * 16 + 8);
        va[u] = *(const uint4*)(row + 96 + h * 16);
        vb[u] = *(const uint4*)(row + 96 + h * 16 + 8);
        const ushort* qrow = qh + (size_t)pc * 96 + h * 16;
        qa[u] = *(const uint4*)qrow;
        qb[u] = *(const uint4*)(qrow + 8);
        xqj[u] = xq[jd[u]];
    };
    PREF_A(0, 0); PREF_A(0, 1); PREF_B(0); PREF_B(1);
    PREF_A(1, 0); PREF_A(1, 1);

    // ---- stage tables into LDS. 6912 16B chunks / 768 thr = 9.
#pragma unroll
    for (int j = 0; j < 9; j++) {
        const int tbl = j / 3;
        const uint4* src = (tbl == 0) ? (const uint4*)rq
                         : (tbl == 1) ? (const uint4*)rk : (const uint4*)rv;
        int rem = t + (j % 3) * 768;               // chunk within table
        int ROW = rem / 12, slot = rem - ROW * 12; // 12 x 16B per 192B row
        uint4 val = src[rem];
        const int base = (tbl == 0) ? 0 : (tbl == 1) ? KOFF : VOFF;
        const int pitch = (tbl == 2) ? VPITCH : QPITCH;
        *(uint4*)(Lb + base + ROW * pitch + slot * 16) = val;
    }
    __syncthreads();

    auto LD2Q = [&](const char* base, int R, uint4& A, uint4& B) {
        const char* rb = base + R * QPITCH + h * 32;
        A = *(const uint4*)rb;
        B = *(const uint4*)(rb + 16);
    };
    auto F2 = [](const uint4& u, int i) -> float2 {
        return __half22float2(((const __half2*)&u)[i]);
    };
    auto H2 = [](const uint4& u, int i) -> __half2 {
        return ((const __half2*)&u)[i];
    };

    const bool e3 = (e & 8) != 0, e2 = (e & 4) != 0;
    const bool e1 = (e & 2) != 0, e0 = (e & 1) != 0;

    for (int it = 0; it < iters; it++) {
        // ---- ridx from packed quantized coords (both streams)
        int i0[2], i1[2], i2[2];
#pragma unroll
        for (int u = 0; u < 2; u++) {
            i0[u] = (int)(xqp[u] & 255u) - (int)(xqj[u] & 255u) + 15;
            i1[u] = (int)((xqp[u] >> 8) & 255u) - (int)((xqj[u] >> 8) & 255u) + 15;
            i2[u] = (int)((xqp[u] >> 16) & 255u) - (int)((xqj[u] >> 16) & 255u) + 15;
        }

        // ---- unpack v rows to fp32 (frees va/vb for the prefetch)
        float f[2][16];
#pragma unroll
        for (int u = 0; u < 2; u++)
#pragma unroll
            for (int i = 0; i < 4; i++) {
                float2 lo = F2(va[u], i), hi = F2(vb[u], i);
                f[u][2 * i] = lo.x; f[u][2 * i + 1] = lo.y;
                f[u][8 + 2 * i] = hi.x; f[u][8 + 2 * i + 1] = hi.y;
            }

        // ---- score: packed-fp16 dot2 (q.k + bias tables from LDS)
        float a[2];
#pragma unroll
        for (int u = 0; u < 2; u++) {
            float x0 = dot2(qa[u].x, ka[u].x, 0.f), x1 = dot2(qa[u].y, ka[u].y, 0.f);
            x0 = dot2(qa[u].z, ka[u].z, x0); x1 = dot2(qa[u].w, ka[u].w, x1);
            x0 = dot2(qb[u].x, kb[u].x, x0); x1 = dot2(qb[u].y, kb[u].y, x1);
            x0 = dot2(qb[u].z, kb[u].z, x0); x1 = dot2(qb[u].w, kb[u].w, x1);
            float bias = 0.f;
#define BIAS_C(ROW)                                                            \
            {                                                                  \
                uint4 ta, tb, ua, ub;                                          \
                LD2Q(Lb, (ROW), ta, tb);                                       \
                LD2Q(Lb + KOFF, (ROW), ua, ub);                                \
                float uu = dot2(qa[u].x, ta.x, 0.f), w = dot2(ka[u].x, ua.x, 0.f);\
                uu = dot2(qa[u].y, ta.y, uu); w = dot2(ka[u].y, ua.y, w);      \
                uu = dot2(qa[u].z, ta.z, uu); w = dot2(ka[u].z, ua.z, w);      \
                uu = dot2(qa[u].w, ta.w, uu); w = dot2(ka[u].w, ua.w, w);      \
                uu = dot2(qb[u].x, tb.x, uu); w = dot2(kb[u].x, ub.x, w);      \
                uu = dot2(qb[u].y, tb.y, uu); w = dot2(kb[u].y, ub.y, w);      \
                uu = dot2(qb[u].z, tb.z, uu); w = dot2(kb[u].z, ub.z, w);      \
                uu = dot2(qb[u].w, tb.w, uu); w = dot2(kb[u].w, ub.w, w);      \
                bias += uu + w;                                                \
            }
            BIAS_C(i0[u])
            BIAS_C(64 + i1[u])
            BIAS_C(128 + i2[u])
#undef BIAS_C
            a[u] = x0 + x1 + bias;
        }

        const int op0 = p[0], op1 = p[1]; (void)op0; (void)op1;
        if (it + 1 < iters) {
            PREF_B(0); PREF_B(1);
            PREF_A(it + 2, 0); PREF_A(it + 2, 1);
        }

        // ---- fold table_v into f: pk_add_f16 pre-sum (err ~3e-5), fp32 add
#pragma unroll
        for (int u = 0; u < 2; u++) {
            uint4 t0a, t0b, t1a, t1b, t2a, t2b;
            {
                const char* rb = Lb + VOFF + i0[u] * VPITCH + h * 32;
                t0a = *(const uint4*)rb; t0b = *(const uint4*)(rb + 16);
            }
            {
                const char* rb = Lb + VOFF + (64 + i1[u]) * VPITCH + h * 32;
                t1a = *(const uint4*)rb; t1b = *(const uint4*)(rb + 16);
            }
            {
                const char* rb = Lb + VOFF + (128 + i2[u]) * VPITCH + h * 32;
                t2a = *(const uint4*)rb; t2b = *(const uint4*)(rb + 16);
            }
#pragma unroll
            for (int i = 0; i < 4; i++) {
                __half2 sa = H2(t0a, i) + H2(t1a, i) + H2(t2a, i);
                __half2 sb = H2(t0b, i) + H2(t1b, i) + H2(t2b, i);
                float2 fa = __half22float2(sa), fb = __half22float2(sb);
                f[u][2 * i]     += fa.x;
                f[u][2 * i + 1] += fa.y;
                f[u][8 + 2 * i]     += fb.x;
                f[u][8 + 2 * i + 1] += fb.y;
            }
        }

        // ---- softmax over the 16-lane group via DPP rotations (no LDS)
        float wgt[2];
#pragma unroll
        for (int u = 0; u < 2; u++) {
            float mx = a[u];
            mx = fmaxf(mx, dppf<0x128>(mx));   // ror 8
            mx = fmaxf(mx, dppf<0x124>(mx));   // ror 4
            mx = fmaxf(mx, dppf<0x122>(mx));   // ror 2
            mx = fmaxf(mx, dppf<0x121>(mx));   // ror 1
            float ex = __expf(a[u] - mx);
            float sum = ex;
            sum += dppf<0x128>(sum);
            sum += dppf<0x124>(sum);
            sum += dppf<0x122>(sum);
            sum += dppf<0x121>(sum);
            wgt[u] = ex * __builtin_amdgcn_rcpf(sum);
        }

        // ---- PV: DPP butterfly transpose-reduce; lane e ends with col e
#pragma unroll
        for (int u = 0; u < 2; u++) {
            float P[16];
#pragma unroll
            for (int c = 0; c < 16; c++) P[c] = wgt[u] * f[u][c];
            float A8[8];
#pragma unroll
            for (int j = 0; j < 8; j++) {      // xor15 (mirror), keep c3=e3
                float kp = e3 ? P[j + 8] : P[j];
                float sd = e3 ? P[j] : P[j + 8];
                A8[j] = kp + dppf<0x140>(sd);
            }
            float B4[4];
#pragma unroll
            for (int j = 0; j < 4; j++) {      // xor7 (half_mirror), keep c2=e2
                float kp = e2 ? A8[j + 4] : A8[j];
                float sd = e2 ? A8[j] : A8[j + 4];
                B4[j] = kp + dppf<0x141>(sd);
            }
            float C2[2];
#pragma unroll
            for (int j = 0; j < 2; j++) {      // xor2 (quad_perm), keep c1=e1
                float kp = e1 ? B4[j + 2] : B4[j];
                float sd = e1 ? B4[j] : B4[j + 2];
                C2[j] = kp + dppf<0x4E>(sd);
            }
            {                                  // xor1 (quad_perm), keep c0=e0
                float kp = e0 ? C2[1] : C2[0];
                float sd = e0 ? C2[0] : C2[1];
                float xres = kp + dppf<0xB1>(sd);
                // x row -> LDS stash (local row = it*16 + u*8 + pt)
                *(ushort*)(Lb + XOFF +
                           (it * PPB + u * 8 + pt) * (XPITCH * 2) + tp * 2) =
                    f2h(xres);
            }
        }
    }
    __syncthreads();  // x-stash complete

    // ---- proj phase: 208 local rows, 32-row wave-jobs (waves 0..6)
    {
        const int wave = t >> 6, lane = t & 63;
        const int m = lane & 15, q = lane >> 4;
        const int row0l = wave * 32;
        const int nloc = iters * PPB;  // 208
        if (row0l < nloc) {
            const ushort* X = (const ushort*)(Lb + XOFF);
            const ushort* wbase = wtproj + (size_t)m * 96 + q * 8;
            int r0 = row0l + m;      if (r0 > nloc - 1) r0 = nloc - 1;
            int r1 = row0l + 16 + m; if (r1 > nloc - 1) r1 = nloc - 1;
            floatx4 acc[2][6];
#pragma unroll
            for (int g = 0; g < 2; g++)
#pragma unroll
                for (int ct = 0; ct < 6; ct++) acc[g][ct] = (floatx4){0.f, 0.f, 0.f, 0.f};
#pragma unroll
            for (int kk = 0; kk < 96; kk += 32) {
                half8 a0 = *(const half8*)(X + r0 * XPITCH + q * 8 + kk);
                half8 a1 = *(const half8*)(X + r1 * XPITCH + q * 8 + kk);
#pragma unroll
                for (int ct = 0; ct < 6; ct++) {
                    half8 bb = *(const half8*)(wbase + ct * 16 * 96 + kk);
                    acc[0][ct] = __builtin_amdgcn_mfma_f32_16x16x32_f16(a0, bb, acc[0][ct], 0, 0, 0);
                    acc[1][ct] = __builtin_amdgcn_mfma_f32_16x16x32_f16(a1, bb, acc[1][ct], 0, 0, 0);
                }
            }
#pragma unroll
            for (int g = 0; g < 2; g++)
#pragma unroll
                for (int ct = 0; ct < 6; ct++) {
                    int col = ct * 16 + m;
                    float bv = b_proj[col];
#pragma unroll
                    for (int r = 0; r < 4; r++) {
                        int lr = row0l + g * 16 + q * 4 + r;
                        if (lr < nloc) {
                            int grow = (lr >> 4) * stride + b * PPB + (lr & 15);
                            if (grow < n)
                                out[(size_t)grow * 96 + col] = acc[g][ct][r] + bv;
                        }
                    }
                }
        }
    }
}

// ---------------------------------------------------------------- launch
extern "C" void kernel_launch(void* const* d_in, const int* in_sizes, int n_in,
                              void* d_out, int out_size, void* d_ws, size_t ws_size,
                              hipStream_t stream) {
    const float* feats   = (const float*)d_in[0];
    const float* xyz     = (const float*)d_in[1];
    const int*   index_1 = (const int*)d_in[5];
    const float* shiftp  = (const float*)d_in[6];
    const float* W_qkv   = (const float*)d_in[7];
    const float* b_qkv   = (const float*)d_in[8];
    const float* table_q = (const float*)d_in[9];
    const float* table_k = (const float*)d_in[10];
    const float* table_v = (const float*)d_in[11];
    const float* W_proj  = (const float*)d_in[12];
    const float* b_proj  = (const float*)d_in[13];
    float* out = (float*)d_out;

    const int n = in_sizes[0] / 96;  // 50000

    float* w = (float*)d_ws;
    float*  mn     = w;                         // 16 floats
    ushort* qbf    = (ushort*)(w + 16);         // n*96 fp16 (pre-scaled q)
    ushort* kvbuf  = qbf + (size_t)n * 96;      // n*192: k fp16 | v fp16
    ushort* wtqkv  = kvbuf + (size_t)n * 192;   // 27648
    ushort* wtproj = wtqkv + 27648;             // 9216
    ushort* rq     = wtproj + 9216;             // 18432 each
    ushort* rk     = rq + 18432;
    ushort* rv     = rk + 18432;
    uint*   xqv    = (uint*)(rv + 18432);       // n packed quantized coords

    // mn init: 0x7F7F7F7F = 3.396e38 (big positive) for atomicMin
    hipMemsetAsync(mn, 0x7F, 3 * sizeof(float), stream);
    prep_min_kernel<<<108, 256, 0, stream>>>(W_qkv, W_proj, table_q, table_k,
                                             table_v, xyz, wtqkv, wtproj,
                                             rq, rk, rv, mn, n);
    qkv_mfma_kernel<<<(n + 63) / 64, 384, 0, stream>>>(feats, wtqkv, b_qkv,
                                                       (uint4*)qbf, (uint4*)kvbuf,
                                                       xyz, mn, shiftp, xqv, n);
    attn_proj_kernel<<<ATTN_NB, 768, 0, stream>>>(qbf, kvbuf, xqv, index_1,
                                                  rq, rk, rv, wtproj, b_proj,
                                                  out, n);
}

// Round 10
// 197.520 us; speedup vs baseline: 1.0341x; 1.0341x over previous
//
#include <hip/hip_runtime.h>
#include <hip/hip_fp16.h>
#include <math.h>

#define FLT_BIG 3.402823466e38f
typedef unsigned int uint;
typedef unsigned short ushort;
typedef __attribute__((ext_vector_type(8))) _Float16 half8;  // 8 fp16 (4 VGPRs)
typedef __attribute__((ext_vector_type(4))) float floatx4;   // MFMA C/D frag

__device__ inline ushort f2h(float f) {   // fp16 RNE, 1 instr (v_cvt_f16_f32)
    return __half_as_ushort(__float2half(f));
}
// packed 2xfp16 dot with f32 accumulate: d = a.h0*b.h0 + a.h1*b.h1 + c
__device__ inline float dot2(uint a, uint b, float c) {
    float d;
    asm("v_dot2_f32_f16 %0, %1, %2, %3" : "=v"(d) : "v"(a), "v"(b), "v"(c));
    return d;
}
// DPP cross-lane read (VALU pipe, not DS). CTRL: 0x120+N=row_ror:N,
// 0x140=row_mirror (xor15), 0x141=row_half_mirror (xor7 within 8),
// 0x4E=quad_perm[2,3,0,1] (xor2), 0xB1=quad_perm[1,0,3,2] (xor1).
template <int CTRL>
__device__ inline float dppf(float x) {
    return __int_as_float(__builtin_amdgcn_update_dpp(
        __float_as_int(x), __float_as_int(x), CTRL, 0xF, 0xF, true));
}

// ---------------------------------------------------------------- prep + min
// Table/W transposes (fp16) + grid-stride xyz-min with atomicMin.
// mn is pre-initialized to 0x7F7F7F7F (3.396e38) by hipMemsetAsync.
__global__ void prep_min_kernel(const float* __restrict__ W_qkv,
                                const float* __restrict__ W_proj,
                                const float* __restrict__ tq, const float* __restrict__ tk,
                                const float* __restrict__ tv,
                                const float* __restrict__ xyz,
                                ushort* __restrict__ wtqkv, ushort* __restrict__ wtproj,
                                ushort* __restrict__ rq, ushort* __restrict__ rk,
                                ushort* __restrict__ rv, float* mn, int n) {
    int tid = blockIdx.x * 256 + threadIdx.x;
    if (tid < 18432) {  // tables: 3*64*96 -> [c][idx][hd] fp16
        int c = tid / 6144, rem = tid - c * 6144;
        int idx = rem / 96, hd = rem - idx * 96;
        int src = (idx * 96 + hd) * 3 + c;
        rq[tid] = f2h(tq[src]);
        rk[tid] = f2h(tk[src]);
        rv[tid] = f2h(tv[src]);
    }
    if (tid < 27648) {  // WT_qkv[j][d] = W_qkv[d][j], j over 288
        int j = tid / 96, d = tid - j * 96;
        wtqkv[tid] = f2h(W_qkv[d * 288 + j]);
    }
    if (tid < 9216) {   // WT_proj[j][d] = W_proj[d][j]
        int j = tid / 96, d = tid - j * 96;
        wtproj[tid] = f2h(W_proj[d * 96 + j]);
    }
    // grid-stride min partials -> wave reduce -> atomicMin (mn preset big)
    float m0 = FLT_BIG, m1 = FLT_BIG, m2 = FLT_BIG;
    for (int i = tid; i < n; i += gridDim.x * 256) {
        m0 = fminf(m0, xyz[3 * i + 0]);
        m1 = fminf(m1, xyz[3 * i + 1]);
        m2 = fminf(m2, xyz[3 * i + 2]);
    }
#pragma unroll
    for (int off = 32; off > 0; off >>= 1) {
        m0 = fminf(m0, __shfl_down(m0, off));
        m1 = fminf(m1, __shfl_down(m1, off));
        m2 = fminf(m2, __shfl_down(m2, off));
    }
    if ((threadIdx.x & 63) == 0) {
        // xyz >= 0 so float bits are monotone under signed int compare
        atomicMin((int*)&mn[0], __float_as_int(m0));
        atomicMin((int*)&mn[1], __float_as_int(m1));
        atomicMin((int*)&mn[2], __float_as_int(m2));
    }
}

// ---------------------------------------------------------------- QKV MFMA GEMM
// ONE pass over A: 384-thread block covers 64 rows; A tile cvt'd fp32->fp16
// ONCE into LDS (pitch 104 ushorts), then 6 waves = 3 channels x 2 row-groups
// consume via ds_read_b128. 56KB LDS -> 2 blocks/CU. Threads 0..63 also
// compute packed quantized coords xq[p] (mn ready by stream order).
__global__ __launch_bounds__(384) void qkv_mfma_kernel(
    const float* __restrict__ A, const ushort* __restrict__ WT,
    const float* __restrict__ bias, uint4* __restrict__ qout4,
    uint4* __restrict__ kvout4, const float* __restrict__ xyz,
    const float* __restrict__ mn, const float* __restrict__ shiftp,
    uint* __restrict__ xq, int n) {
    __shared__ ushort Ash[64 * 104];     // 13312 B: A tile fp16, pitch 208B
    __shared__ ushort lds[6][32 * 112];  // 43008 B: per-wave epilogue repack
    const int t = threadIdx.x;
    const int row0 = blockIdx.x * 64;

    if (t < 64) {
        int rp = row0 + t;
        if (rp < n) {
            float shift = shiftp[0];
            float q0 = floorf(fmodf(xyz[3 * rp + 0] - mn[0] + shift, 4.0f) * 4.0f);
            float q1 = floorf(fmodf(xyz[3 * rp + 1] - mn[1] + shift, 4.0f) * 4.0f);
            float q2 = floorf(fmodf(xyz[3 * rp + 2] - mn[2] + shift, 4.0f) * 4.0f);
            xq[rp] = (uint)(int)q0 | ((uint)(int)q1 << 8) | ((uint)(int)q2 << 16);
        }
    }

    // ---- stage A tile: 64 rows x 24 float4 = 1536 chunks, 4 per thread
    const float4* A4 = (const float4*)A;
#pragma unroll
    for (int j = 0; j < 4; j++) {
        int idx = t + j * 384;
        int row = idx / 24, c4 = idx - row * 24;
        int gr = row0 + row; if (gr > n - 1) gr = n - 1;
        float4 v = A4[(size_t)gr * 24 + c4];
        uint2 pk;
        pk.x = (uint)f2h(v.x) | ((uint)f2h(v.y) << 16);
        pk.y = (uint)f2h(v.z) | ((uint)f2h(v.w) << 16);
        *(uint2*)&Ash[row * 104 + c4 * 4] = pk;
    }
    __syncthreads();

    const int wave = t >> 6, lane = t & 63;
    const int ch = wave >> 1, rg = wave & 1;  // 3 channels x 2 row-groups
    const int m = lane & 15, q = lane >> 4;
    const int wrow0 = row0 + rg * 32;

    const ushort* wbase = WT + ((size_t)ch * 96 + m) * 96 + q * 8;

    floatx4 acc[2][6];
#pragma unroll
    for (int g = 0; g < 2; g++)
#pragma unroll
        for (int ct = 0; ct < 6; ct++) acc[g][ct] = (floatx4){0.f, 0.f, 0.f, 0.f};

#pragma unroll
    for (int kk4 = 0; kk4 < 24; kk4 += 8) {  // k offset in float4 units
        half8 a0 = *(const half8*)&Ash[(rg * 32 + m) * 104 + (kk4 + q * 2) * 4];
        half8 a1 = *(const half8*)&Ash[(rg * 32 + 16 + m) * 104 + (kk4 + q * 2) * 4];
#pragma unroll
        for (int ct = 0; ct < 6; ct++) {
            half8 b = *(const half8*)(wbase + ct * 16 * 96 + kk4 * 4);
            acc[0][ct] = __builtin_amdgcn_mfma_f32_16x16x32_f16(a0, b, acc[0][ct], 0, 0, 0);
            acc[1][ct] = __builtin_amdgcn_mfma_f32_16x16x32_f16(a1, b, acc[1][ct], 0, 0, 0);
        }
    }

    ushort* L = lds[wave];
    const float sc = (ch == 0) ? 0.25f : 1.0f;
#pragma unroll
    for (int g = 0; g < 2; g++)
#pragma unroll
        for (int ct = 0; ct < 6; ct++) {
            float bv = bias[ch * 96 + ct * 16 + m];
#pragma unroll
            for (int r = 0; r < 4; r++) {
                int rowl = g * 16 + q * 4 + r;
                L[rowl * 112 + ct * 16 + m] = f2h((acc[g][ct][r] + bv) * sc);
            }
        }
    // wave-internal LDS RAW: compiler inserts lgkmcnt wait, no barrier needed
    const int strideU4 = (ch == 0) ? 12 : 24;
    const int offU4 = (ch == 2) ? 12 : 0;
    uint4* dst = (ch == 0) ? qout4 : kvout4;
#pragma unroll
    for (int i = 0; i < 6; i++) {
        int idx = i * 64 + lane;  // 0..383 over 32 rows x 12 uint4
        int rowl = idx / 12, u4 = idx - rowl * 12;
        int grow = wrow0 + rowl;
        if (grow < n) {
            uint4 val = *(const uint4*)(L + rowl * 112 + u4 * 8);
            dst[(size_t)grow * strideU4 + offU4 + u4] = val;
        }
    }
}

// ---------------------------------------------------------------- attn + proj
// One 768-thread block per CU (grid 256). LDS: rq/rk pitch 208, rv pitch 192
// XOR-swizzled (116736 B) + x-stash 200 rows x 208 B (41600 B) = 158336 B.
// R8 structure, with the per-iteration body SOFTWARE-PIPELINED INTRA-WAVE:
// all 18 table ds_reads (9 row-pairs) are hoisted into named registers at the
// top of the iteration, so the compiler's staged lgkmcnt waits let row-0 dot2s
// overlap rows 1-8 completing in the DS pipe — removing the load->16-dep-dot2
// ping-pong that left VALU and DS each at ~50% with no overlap (R8 counters:
// 36us VALU + 38us DS ~= 74.7us wall). VGPR ~140, 3 waves/SIMD enforced.
// x rows land in LDS; proj runs per-block after one barrier.
#define ATTN_NB 256
#define ATTN_B 8
#define QPITCH 208
#define VPITCH 192
#define KOFF 39936   // 192 rows x 208
#define VOFF 79872   // + 192 rows x 208
#define XOFF 116736  // + 192 rows x 192
#define XPITCH 104   // ushorts (208 B)
__global__ __launch_bounds__(768, 3) void attn_proj_kernel(
    const ushort* __restrict__ qh, const ushort* __restrict__ kv,
    const uint* __restrict__ xq, const int* __restrict__ index_1,
    const ushort* __restrict__ rq, const ushort* __restrict__ rk,
    const ushort* __restrict__ rv, const ushort* __restrict__ wtproj,
    const float* __restrict__ b_proj, float* __restrict__ out, int n) {
    __shared__ __align__(16) char Lb[158336];

    const int t = threadIdx.x, b = blockIdx.x;
    const int pt = t / 96, tp = t - pt * 96;
    const int h = tp >> 4, e = tp & 15;

    const int stride = ATTN_NB * ATTN_B;                   // 2048
    const int iters = (n + stride - 1) / stride;           // 25

    // ---- 2-stage prefetch state
    int pA, jdA; uint xqpA;                                // stage A: indices
    auto PREF_A = [&](int it) {
        pA = (it * ATTN_NB + b) * ATTN_B + pt;
        int pc = pA < n ? pA : n - 1;
        jdA = index_1[(size_t)pc * 16 + e];
        xqpA = xq[pc];
    };
    int p, jd; uint xqp, xqj;                              // stage B: rows
    uint4 ka, kb, va, vb, qa, qb;
    auto PREF_B = [&]() {
        p = pA; jd = jdA; xqp = xqpA;
        int pc = p < n ? p : n - 1;
        const ushort* row = kv + (size_t)jd * 192;
        ka = *(const uint4*)(row + h * 16);
        kb = *(const uint4*)(row + h * 16 + 8);
        va = *(const uint4*)(row + 96 + h * 16);
        vb = *(const uint4*)(row + 96 + h * 16 + 8);
        const ushort* qrow = qh + (size_t)pc * 96 + h * 16;
        qa = *(const uint4*)qrow;
        qb = *(const uint4*)(qrow + 8);
        xqj = xq[jd];
    };
    PREF_A(0); PREF_B(); PREF_A(1);

    // ---- stage tables into LDS. 6912 16B chunks / 768 thr = 9.
    // rv rows get a 16B-slot XOR swizzle (plain pitch-192 puts every row at
    // bank 0/16: 192B = 48 dwords, 48R mod 32 = 16(R&1)).
#pragma unroll
    for (int j = 0; j < 9; j++) {
        const int tbl = j / 3;
        const uint4* src = (tbl == 0) ? (const uint4*)rq
                         : (tbl == 1) ? (const uint4*)rk : (const uint4*)rv;
        int rem = t + (j % 3) * 768;               // chunk within table
        int ROW = rem / 12, slot = rem - ROW * 12; // 12 x 16B per 192B row
        uint4 val = src[rem];
        const int base = (tbl == 0) ? 0 : (tbl == 1) ? KOFF : VOFF;
        const int pitch = (tbl == 2) ? VPITCH : QPITCH;
        int off = slot * 16;
        if (tbl == 2) off ^= ((ROW >> 1) & 3) << 4;
        *(uint4*)(Lb + base + ROW * pitch + off) = val;
    }
    __syncthreads();

    auto LD2Q = [&](const char* base, int R, uint4& A, uint4& B) {
        const char* rb = base + R * QPITCH + h * 32;
        A = *(const uint4*)rb;
        B = *(const uint4*)(rb + 16);
    };
    auto LDV = [&](int R, uint4& A, uint4& B) {
        int x = ((R >> 1) & 3) << 4;
        const char* rb = Lb + VOFF + R * VPITCH;
        A = *(const uint4*)(rb + ((h * 32) ^ x));
        B = *(const uint4*)(rb + ((h * 32 + 16) ^ x));
    };
    auto F2 = [](const uint4& u, int i) -> float2 {
        return __half22float2(((const __half2*)&u)[i]);
    };

    const bool b3 = (e & 8) != 0, b2 = (e & 4) != 0;
    const bool b1 = (e & 2) != 0, b0 = (e & 1) != 0;

    for (int it = 0; it < iters; it++) {
        // ---- ridx from packed quantized coords
        const int i0 = (int)(xqp & 255u) - (int)(xqj & 255u) + 15;
        const int i1 = (int)((xqp >> 8) & 255u) - (int)((xqj >> 8) & 255u) + 15;
        const int i2 = (int)((xqp >> 16) & 255u) - (int)((xqj >> 16) & 255u) + 15;

        // ---- HOISTED table loads: all 9 row-pairs issue back-to-back; the
        // compiler's staged lgkmcnt lets row-0 dot2s overlap rows 1-8.
        uint4 q0a, q0b, q1a, q1b, q2a, q2b;
        uint4 k0a, k0b, k1a, k1b, k2a, k2b;
        uint4 v0a, v0b, v1a, v1b, v2a, v2b;
        LD2Q(Lb, i0, q0a, q0b);
        LD2Q(Lb, 64 + i1, q1a, q1b);
        LD2Q(Lb, 128 + i2, q2a, q2b);
        LD2Q(Lb + KOFF, i0, k0a, k0b);
        LD2Q(Lb + KOFF, 64 + i1, k1a, k1b);
        LD2Q(Lb + KOFF, 128 + i2, k2a, k2b);
        LDV(i0, v0a, v0b);
        LDV(64 + i1, v1a, v1b);
        LDV(128 + i2, v2a, v2b);

        // ---- unpack v row to fp32 (frees va/vb for the prefetch)
        float f[16];
#pragma unroll
        for (int i = 0; i < 4; i++) {
            float2 lo = F2(va, i), hi = F2(vb, i);
            f[2 * i] = lo.x; f[2 * i + 1] = lo.y;
            f[8 + 2 * i] = hi.x; f[8 + 2 * i + 1] = hi.y;
        }

        // ---- score: packed-fp16 dot2 (q.k + bias tables from registers)
        float a;
        {
            float x0 = dot2(qa.x, ka.x, 0.f), x1 = dot2(qa.y, ka.y, 0.f);
            x0 = dot2(qa.z, ka.z, x0); x1 = dot2(qa.w, ka.w, x1);
            x0 = dot2(qb.x, kb.x, x0); x1 = dot2(qb.y, kb.y, x1);
            x0 = dot2(qb.z, kb.z, x0); x1 = dot2(qb.w, kb.w, x1);
            float bias = 0.f;
#define BIAS_C(TA, TB, UA, UB)                                                 \
            {                                                                  \
                float u = dot2(qa.x, TA.x, 0.f), w = dot2(ka.x, UA.x, 0.f);    \
                u = dot2(qa.y, TA.y, u); w = dot2(ka.y, UA.y, w);              \
                u = dot2(qa.z, TA.z, u); w = dot2(ka.z, UA.z, w);              \
                u = dot2(qa.w, TA.w, u); w = dot2(ka.w, UA.w, w);              \
                u = dot2(qb.x, TB.x, u); w = dot2(kb.x, UB.x, w);              \
                u = dot2(qb.y, TB.y, u); w = dot2(kb.y, UB.y, w);              \
                u = dot2(qb.z, TB.z, u); w = dot2(kb.z, UB.z, w);              \
                u = dot2(qb.w, TB.w, u); w = dot2(kb.w, UB.w, w);              \
                bias += u + w;                                                 \
            }
            BIAS_C(q0a, q0b, k0a, k0b)
            BIAS_C(q1a, q1b, k1a, k1b)
            BIAS_C(q2a, q2b, k2a, k2b)
#undef BIAS_C
            a = x0 + x1 + bias;
        }

        if (it + 1 < iters) { PREF_B(); PREF_A(it + 2); }

        // ---- fold table_v into f (fp32 accumulate, from registers)
#pragma unroll
        for (int i = 0; i < 4; i++) {
            float2 a0 = F2(v0a, i), a1 = F2(v1a, i), a2 = F2(v2a, i);
            f[2 * i]     += a0.x + a1.x + a2.x;
            f[2 * i + 1] += a0.y + a1.y + a2.y;
            float2 c0 = F2(v0b, i), c1 = F2(v1b, i), c2 = F2(v2b, i);
            f[8 + 2 * i]     += c0.x + c1.x + c2.x;
            f[8 + 2 * i + 1] += c0.y + c1.y + c2.y;
        }

        // ---- softmax over the 16-lane group via DPP rotations (no LDS)
        float wgt;
        {
            float mx = a;
            mx = fmaxf(mx, dppf<0x128>(mx));   // ror 8
            mx = fmaxf(mx, dppf<0x124>(mx));   // ror 4
            mx = fmaxf(mx, dppf<0x122>(mx));   // ror 2
            mx = fmaxf(mx, dppf<0x121>(mx));   // ror 1
            float ex = __expf(a - mx);
            float sum = ex;
            sum += dppf<0x128>(sum);
            sum += dppf<0x124>(sum);
            sum += dppf<0x122>(sum);
            sum += dppf<0x121>(sum);
            wgt = ex * __builtin_amdgcn_rcpf(sum);
        }

        // ---- PV: DPP butterfly transpose-reduce; lane e ends with col e
        float P[16];
#pragma unroll
        for (int c = 0; c < 16; c++) P[c] = wgt * f[c];
        float A8[8];
#pragma unroll
        for (int j = 0; j < 8; j++) {          // xor15 (mirror), keep c3=e3
            float kp = b3 ? P[j + 8] : P[j];
            float sd = b3 ? P[j] : P[j + 8];
            A8[j] = kp + dppf<0x140>(sd);
        }
        float B4[4];
#pragma unroll
        for (int j = 0; j < 4; j++) {          // xor7 (half_mirror), keep c2=e2
            float kp = b2 ? A8[j + 4] : A8[j];
            float sd = b2 ? A8[j] : A8[j + 4];
            B4[j] = kp + dppf<0x141>(sd);
        }
        float C2[2];
#pragma unroll
        for (int j = 0; j < 2; j++) {          // xor2 (quad_perm), keep c1=e1
            float kp = b1 ? B4[j + 2] : B4[j];
            float sd = b1 ? B4[j] : B4[j + 2];
            C2[j] = kp + dppf<0x4E>(sd);
        }
        {                                      // xor1 (quad_perm), keep c0=e0
            float kp = b0 ? C2[1] : C2[0];
            float sd = b0 ? C2[0] : C2[1];
            float xres = kp + dppf<0xB1>(sd);
            // x row -> LDS stash (local row = it*8+pt); 2B/lane contiguous
            *(ushort*)(Lb + XOFF + (it * ATTN_B + pt) * (XPITCH * 2) + tp * 2) =
                f2h(xres);
        }
    }
    __syncthreads();  // x-stash complete

    // ---- proj phase: 200 local rows, 32-row wave-jobs (waves 0..6)
    {
        const int wave = t >> 6, lane = t & 63;
        const int m = lane & 15, q = lane >> 4;
        const int row0l = wave * 32;
        const int nloc = iters * ATTN_B;  // 200
        if (row0l < nloc) {
            const ushort* X = (const ushort*)(Lb + XOFF);
            const ushort* wbase = wtproj + (size_t)m * 96 + q * 8;
            int r0 = row0l + m;      if (r0 > nloc - 1) r0 = nloc - 1;
            int r1 = row0l + 16 + m; if (r1 > nloc - 1) r1 = nloc - 1;
            floatx4 acc[2][6];
#pragma unroll
            for (int g = 0; g < 2; g++)
#pragma unroll
                for (int ct = 0; ct < 6; ct++) acc[g][ct] = (floatx4){0.f, 0.f, 0.f, 0.f};
#pragma unroll
            for (int kk = 0; kk < 96; kk += 32) {
                half8 a0 = *(const half8*)(X + r0 * XPITCH + q * 8 + kk);
                half8 a1 = *(const half8*)(X + r1 * XPITCH + q * 8 + kk);
#pragma unroll
                for (int ct = 0; ct < 6; ct++) {
                    half8 bb = *(const half8*)(wbase + ct * 16 * 96 + kk);
                    acc[0][ct] = __builtin_amdgcn_mfma_f32_16x16x32_f16(a0, bb, acc[0][ct], 0, 0, 0);
                    acc[1][ct] = __builtin_amdgcn_mfma_f32_16x16x32_f16(a1, bb, acc[1][ct], 0, 0, 0);
                }
            }
#pragma unroll
            for (int g = 0; g < 2; g++)
#pragma unroll
                for (int ct = 0; ct < 6; ct++) {
                    int col = ct * 16 + m;
                    float bv = b_proj[col];
#pragma unroll
                    for (int r = 0; r < 4; r++) {
                        int lr = row0l + g * 16 + q * 4 + r;
                        if (lr < nloc) {
                            int grow = (lr >> 3) * stride + b * ATTN_B + (lr & 7);
                            if (grow < n)
                                out[(size_t)grow * 96 + col] = acc[g][ct][r] + bv;
                        }
                    }
                }
        }
    }
}

// ---------------------------------------------------------------- launch
extern "C" void kernel_launch(void* const* d_in, const int* in_sizes, int n_in,
                              void* d_out, int out_size, void* d_ws, size_t ws_size,
                              hipStream_t stream) {
    const float* feats   = (const float*)d_in[0];
    const float* xyz     = (const float*)d_in[1];
    const int*   index_1 = (const int*)d_in[5];
    const float* shiftp  = (const float*)d_in[6];
    const float* W_qkv   = (const float*)d_in[7];
    const float* b_qkv   = (const float*)d_in[8];
    const float* table_q = (const float*)d_in[9];
    const float* table_k = (const float*)d_in[10];
    const float* table_v = (const float*)d_in[11];
    const float* W_proj  = (const float*)d_in[12];
    const float* b_proj  = (const float*)d_in[13];
    float* out = (float*)d_out;

    const int n = in_sizes[0] / 96;  // 50000

    float* w = (float*)d_ws;
    float*  mn     = w;                         // 16 floats
    ushort* qbf    = (ushort*)(w + 16);         // n*96 fp16 (pre-scaled q)
    ushort* kvbuf  = qbf + (size_t)n * 96;      // n*192: k fp16 | v fp16
    ushort* wtqkv  = kvbuf + (size_t)n * 192;   // 27648
    ushort* wtproj = wtqkv + 27648;             // 9216
    ushort* rq     = wtproj + 9216;             // 18432 each
    ushort* rk     = rq + 18432;
    ushort* rv     = rk + 18432;
    uint*   xqv    = (uint*)(rv + 18432);       // n packed quantized coords

    // mn init: 0x7F7F7F7F = 3.396e38 (big positive) for atomicMin
    hipMemsetAsync(mn, 0x7F, 3 * sizeof(float), stream);
    prep_min_kernel<<<108, 256, 0, stream>>>(W_qkv, W_proj, table_q, table_k,
                                             table_v, xyz, wtqkv, wtproj,
                                             rq, rk, rv, mn, n);
    qkv_mfma_kernel<<<(n + 63) / 64, 384, 0, stream>>>(feats, wtqkv, b_qkv,
                                                       (uint4*)qbf, (uint4*)kvbuf,
                                                       xyz, mn, shiftp, xqv, n);
    attn_proj_kernel<<<ATTN_NB, 768, 0, stream>>>(qbf, kvbuf, xqv, index_1,
                                                  rq, rk, rv, wtproj, b_proj,
                                                  out, n);
}